// Round 16
// baseline (293.625 us; speedup 1.0000x reference)
//
#include <hip/hip_runtime.h>

// ShallowSIRENWithPosEmb — fp16 hi + fp8-residual X fed DIRECTLY to fp8 MFMA.
// Terms: D = Wh(f16)*Xh(f16) + Wl'(f16,x2^10)*(Xh*2^-10) + (Wh*2^-6 bf8)*(Xl*2^6 fp8).
// R16 = R15 + s_setprio(1) around the 12-MFMA cluster (T5: unsynced wave phases
// -> scheduler role diversity, attn-like regime). All else identical to R15.
// 64 pts/block, 256 thr, 12 MFMA/kstep, no K-loop barriers, LDS 48KB -> 3 blocks/CU.

#define SCALE_F 8.333333333333334f   // 2/0.24

typedef _Float16 hf;
typedef __attribute__((ext_vector_type(2)))  float f32x2;
typedef __attribute__((ext_vector_type(2)))  _Float16 hf2;
typedef __attribute__((ext_vector_type(8)))  _Float16 hf8;
typedef __attribute__((ext_vector_type(16))) float f32x16;

#define WH8_BASE 311296   // ushort offset of bf8 Wh plane in d_ws

// ---- Cody-Waite sin/cos in radians (embeds: args up to ~2e4) ----
__device__ __forceinline__ float redrev(float x) {
  const float chi = 0.15915494309189535f;
  const float clo = 6.4206383e-09f;
  float n = rintf(x * chi);
  float d = __builtin_fmaf(x, chi, -n);
  return __builtin_fmaf(x, clo, d);
}
__device__ __forceinline__ float fsin(float x) { return __builtin_amdgcn_sinf(redrev(x)); }
__device__ __forceinline__ float fcos(float x) { return __builtin_amdgcn_cosf(redrev(x)); }
// rev-space film sin: v_fract + v_sin (sin periodic in 1 rev)
__device__ __forceinline__ float sinrev(float t) {
  return __builtin_amdgcn_sinf(t - floorf(t));
}

#define INV2PI 0.15915494309189535f
#define C15R   2.3873241463784303f   // 15/(2pi)
#define C30R   4.7746482927568605f   // 30/(2pi)

__device__ __forceinline__ unsigned pk2h(hf a, hf b) {
  return ((unsigned)__builtin_bit_cast(unsigned short, a)) |
         (((unsigned)__builtin_bit_cast(unsigned short, b)) << 16);
}
// fp8 e4m3 encode (HW): 4 floats -> 4 bytes
__device__ __forceinline__ unsigned enc4_fp8(float r0, float r1, float r2, float r3) {
  int e = __builtin_amdgcn_cvt_pk_fp8_f32(r0, r1, 0, false);
  e = __builtin_amdgcn_cvt_pk_fp8_f32(r2, r3, e, true);
  return (unsigned)e;
}

// ---- weight prep: fp16 hi + (lo*2^10) slabs + bf8 (hi*2^-6) pair-plane ----
// fp16 slab (8192 ushort/kstep): [hi:4096][lo:4096]; r = [ot:8][kh:2][o5:32][j:8]
// bf8 plane (4096 B/kstep): [ow:4][kh:2][o5:32][oi:2][j:8] -> lane reads ONE uint4.
// L1 slabs 0-3; L2 4-19; L3 20-37 (K=[x2(256)|de27 pad5]).
__global__ void prep_w(const float* __restrict__ W1, const float* __restrict__ W2,
                       const float* __restrict__ Wcs, unsigned short* __restrict__ wsu)
{
  int t = blockIdx.x * 256 + threadIdx.x;
  if (t >= 155648) return;
  int L, pos, base;
  if (t < 16384)      { L = 0; pos = t;         base = 0; }
  else if (t < 81920) { L = 1; pos = t - 16384; base = 32768; }
  else                { L = 2; pos = t - 81920; base = 163840; }
  int kstep = pos >> 12, r = pos & 4095;
  int ot = (r >> 9) & 7, kh = (r >> 8) & 1, o5 = (r >> 3) & 31, j = r & 7;
  int o = ot * 32 + o5, k = kstep * 16 + kh * 8 + j;
  float wv = 0.f;
  if (L == 0)      { if (k < 63) wv = W1[o * 63 + k]; }
  else if (L == 1) { wv = W2[o * 256 + k]; }
  else { if (k < 256) wv = Wcs[o * 283 + 27 + k];
         else { int q = k - 256; if (q < 27) wv = Wcs[o * 283 + q]; } }
  hf hh = (hf)wv;
  hf ll = (hf)((wv - (float)hh) * 1024.0f);
  wsu[base + kstep * 8192 + r]        = __builtin_bit_cast(unsigned short, hh);
  wsu[base + kstep * 8192 + 4096 + r] = __builtin_bit_cast(unsigned short, ll);
  // bf8 plane: Wh * 2^-6 (e5m2), pair layout for 16B lane loads
  int slab = (base >> 13) + kstep;
  int ow2 = ot >> 1, oi = ot & 1;
  int na = ow2 * 1024 + kh * 512 + o5 * 16 + oi * 8 + j;
  unsigned char b8 = (unsigned char)(__builtin_amdgcn_cvt_pk_bf8_f32(
                         (float)hh * 0.015625f, 0.f, 0, false) & 0xff);
  ((unsigned char*)(wsu + WH8_BASE))[slab * 4096 + na] = b8;
}

__device__ __forceinline__ float peval(float x0, float x1, float x2, int k) {
  if (k >= 63) return 0.f;
  if (k < 3) return (k == 0) ? x0 : ((k == 1) ? x1 : x2);
  int rr = k - 3, f = rr / 6, rem = rr - f * 6;
  int d = (rem < 3) ? rem : rem - 3;
  float xa = (d == 0) ? x0 : ((d == 1) ? x1 : x2);
  float arg = xa * (float)(1 << f);
  return (rem < 3) ? fsin(arg) : fcos(arg);
}
__device__ __forceinline__ float deval(float r0, float r1, float r2, int k) {
  if (k >= 27) return 0.f;
  if (k < 3) return (k == 0) ? r0 : ((k == 1) ? r1 : r2);
  int rr = k - 3, f = rr / 6, rem = rr - f * 6;
  int d = (rem < 3) ? rem : rem - 3;
  float ra = (d == 0) ? r0 : ((d == 1) ? r1 : r2);
  float arg = ra * (float)(1 << f);
  return (rem < 3) ? fsin(arg) : fcos(arg);
}
// de B-frags: hi fp16 + residual packed as fp8 e4m3 (x2^6), register-resident
__device__ __forceinline__ void build_de(float r0, float r1, float r2, int kbase,
                                         hf8& hh, uint2& lenc) {
  unsigned uh[4]; float res[8];
  #pragma unroll
  for (int jj = 0; jj < 4; ++jj) {
    float va = deval(r0, r1, r2, kbase + 2 * jj), vb = deval(r0, r1, r2, kbase + 2 * jj + 1);
    hf ha = (hf)va, hb = (hf)vb;
    uh[jj] = pk2h(ha, hb);
    res[2 * jj]     = (va - (float)ha) * 64.f;
    res[2 * jj + 1] = (vb - (float)hb) * 64.f;
  }
  uint4 vh = make_uint4(uh[0], uh[1], uh[2], uh[3]);
  hh = __builtin_bit_cast(hf8, vh);
  lenc = make_uint2(enc4_fp8(res[0], res[1], res[2], res[3]),
                    enc4_fp8(res[4], res[5], res[6], res[7]));
}

// ---- one kstep: 12 MFMAs (2 ot x 2 pt x 3 terms); term3 = bf8_fp8 direct ----
__device__ __forceinline__ void kstep_mfma(uint4 uh0, uint4 uh1, uint4 ul0, uint4 ul1,
                                           uint4 w8q,
                                           hf8 BhA, uint2 BlA, hf8 BhB, uint2 BlB,
                                           f32x16& a00, f32x16& a01,
                                           f32x16& a10, f32x16& a11) {
  const hf sc = (hf)0.0009765625f;               // 2^-10, exact
  hf8 BhsA = BhA * sc, BhsB = BhB * sc;
  hf8 Ah0 = __builtin_bit_cast(hf8, uh0);
  hf8 Ah1 = __builtin_bit_cast(hf8, uh1);
  hf8 Al0 = __builtin_bit_cast(hf8, ul0);
  hf8 Al1 = __builtin_bit_cast(hf8, ul1);
  long A80 = __builtin_bit_cast(long, make_uint2(w8q.x, w8q.y));
  long A81 = __builtin_bit_cast(long, make_uint2(w8q.z, w8q.w));
  long B8A = __builtin_bit_cast(long, BlA), B8B = __builtin_bit_cast(long, BlB);
  __builtin_amdgcn_s_setprio(1);                 // T5: favor MFMA-issuing wave
  a00 = __builtin_amdgcn_mfma_f32_32x32x16_f16(Ah0, BhA,  a00, 0, 0, 0);
  a10 = __builtin_amdgcn_mfma_f32_32x32x16_f16(Ah1, BhA,  a10, 0, 0, 0);
  a01 = __builtin_amdgcn_mfma_f32_32x32x16_f16(Ah0, BhB,  a01, 0, 0, 0);
  a11 = __builtin_amdgcn_mfma_f32_32x32x16_f16(Ah1, BhB,  a11, 0, 0, 0);
  a00 = __builtin_amdgcn_mfma_f32_32x32x16_f16(Al0, BhsA, a00, 0, 0, 0);
  a10 = __builtin_amdgcn_mfma_f32_32x32x16_f16(Al1, BhsA, a10, 0, 0, 0);
  a01 = __builtin_amdgcn_mfma_f32_32x32x16_f16(Al0, BhsB, a01, 0, 0, 0);
  a11 = __builtin_amdgcn_mfma_f32_32x32x16_f16(Al1, BhsB, a11, 0, 0, 0);
  a00 = __builtin_amdgcn_mfma_f32_32x32x16_bf8_fp8(A80, B8A, a00, 0, 0, 0);
  a10 = __builtin_amdgcn_mfma_f32_32x32x16_bf8_fp8(A81, B8A, a10, 0, 0, 0);
  a01 = __builtin_amdgcn_mfma_f32_32x32x16_bf8_fp8(A80, B8B, a01, 0, 0, 0);
  a11 = __builtin_amdgcn_mfma_f32_32x32x16_bf8_fp8(A81, B8B, a11, 0, 0, 0);
  __builtin_amdgcn_s_setprio(0);
}

// ---- one layer: NK ksteps, no barriers; W (incl bf8) prefetched 1 kstep ahead,
//      B-frags loaded at kstep top (R12 pattern — no extra live state) ----
template <int NK, bool DE>
__device__ __forceinline__ void layer_loop(
    const unsigned short* __restrict__ prep, const unsigned char* __restrict__ wh8,
    const unsigned short* lXh, const unsigned char* lXl,
    int ptA, int ptB, int h, int wbA, int w8i,
    f32x16& a00, f32x16& a01, f32x16& a10, f32x16& a11,
    hf8 dhA0, hf8 dhA1, uint2 dlA0, uint2 dlA1,
    hf8 dhB0, hf8 dhB1, uint2 dlB0, uint2 dlB1)
{
  const int bhA = ptA * 256, pA7 = ptA & 7, pA15 = ptA & 15;
  const int bhB = ptB * 256, pB7 = ptB & 7, pB15 = ptB & 15;
  const uint4* wp = (const uint4*)prep;
  const uint4* w8p = (const uint4*)wh8;
  const int wi = wbA >> 3;
  uint4 h0 = wp[wi], h1 = wp[wi + 64];
  uint4 l0 = wp[wi + 512], l1 = wp[wi + 576];
  uint4 w8 = w8p[w8i];
  #pragma unroll 2
  for (int ks = 0; ks < NK; ++ks) {
    uint4 nh0, nh1, nl0, nl1, nw8;
    if (ks + 1 < NK) {                     // prefetch next kstep's W frags (5 x 16B)
      const uint4* np = wp + (size_t)(ks + 1) * 1024;
      nh0 = np[wi]; nh1 = np[wi + 64]; nl0 = np[wi + 512]; nl1 = np[wi + 576];
      nw8 = w8p[(ks + 1) * 256 + w8i];
    }
    hf8 BhA, BhB; uint2 BlA, BlB;
    if (!DE || ks < NK - 2) {
      int slot = ks * 2 + h;
      BhA = *(const hf8*)&lXh[bhA + ((slot ^ pA7) << 3)];
      BhB = *(const hf8*)&lXh[bhB + ((slot ^ pB7) << 3)];
      BlA = *(const uint2*)&lXl[bhA + ((slot ^ pA15) << 3)];
      BlB = *(const uint2*)&lXl[bhB + ((slot ^ pB15) << 3)];
    } else if (ks == NK - 2) {
      BhA = dhA0; BlA = dlA0; BhB = dhB0; BlB = dlB0;
    } else {
      BhA = dhA1; BlA = dlA1; BhB = dhB1; BlB = dlB1;
    }
    kstep_mfma(h0, h1, l0, l1, w8, BhA, BlA, BhB, BlB, a00, a01, a10, a11);
    h0 = nh0; h1 = nh1; l0 = nl0; l1 = nl1; w8 = nw8;
  }
}

// store 4 film outputs: fp16 hi (8B) + fp8 residual (4B)
__device__ __forceinline__ void store4(unsigned short* lXh, unsigned char* lXl,
                                       int pt, int slot, int h,
                                       float v0, float v1, float v2, float v3)
{
  hf h0 = (hf)v0, h1 = (hf)v1, h2 = (hf)v2, h3 = (hf)v3;
  *(uint2*)&lXh[pt * 256 + ((slot ^ (pt & 7)) << 3) + h * 4] =
      make_uint2(pk2h(h0, h1), pk2h(h2, h3));
  *(unsigned*)&lXl[pt * 256 + ((slot ^ (pt & 15)) << 3) + h * 4] =
      enc4_fp8((v0 - (float)h0) * 64.f, (v1 - (float)h1) * 64.f,
               (v2 - (float)h2) * 64.f, (v3 - (float)h3) * 64.f);
}

__global__ void __launch_bounds__(256, 3)
siren_mfma(const float* __restrict__ input, const float* __restrict__ rdir,
           const float* __restrict__ sn, const float* __restrict__ sc,
           const float* __restrict__ b1, const float* __restrict__ b2,
           const float* __restrict__ Wf, const float* __restrict__ bfp,
           const float* __restrict__ bcs, const float* __restrict__ Wcl,
           const float* __restrict__ bcl, const unsigned short* __restrict__ wsu,
           float* __restrict__ out)
{
  __shared__ __align__(16) unsigned char smem[49152];   // 48KB -> 3 blocks/CU
  unsigned short* lXh = (unsigned short*)smem;          // 32KB [pt:64][256 fp16]
  unsigned char*  lXl = smem + 32768;                   // 16KB [pt:64][256 fp8]
  float* lP = (float*)smem;                             // epilogue alias

  const int tid = threadIdx.x;
  const int ow = tid >> 6, lane = tid & 63;             // 4 waves = 4 out-quarters
  const int l31 = lane & 31, h = lane >> 5;
  const int gpt0 = blockIdx.x << 6;                     // 64 pts/block
  const int b = blockIdx.x >> 10;                       // 1024 blocks per batch
  const int ptA = l31, ptB = 32 + l31;
  const int wbA = ow * 1024 + h * 256 + l31 * 8;        // fp16 A-frag base (ushorts)
  const int w8i = ow * 64 + h * 32 + l31;               // bf8 pair-frag uint4 index
  const float* snb = sn + b * 1024;
  const float* scb = sc + b * 512;
  const unsigned char* wh8b = (const unsigned char*)(wsu + WH8_BASE);

  float rA0, rA1, rA2, rB0, rB1, rB2;
  {
    const float* rp = rdir + (size_t)(gpt0 + ptA) * 3;
    rA0 = rp[0]; rA1 = rp[1]; rA2 = rp[2];
    const float* rq = rdir + (size_t)(gpt0 + ptB) * 3;
    rB0 = rq[0]; rB1 = rq[1]; rB2 = rq[2];
  }

  // ---- embed: pe (K=64, k=63 pad) -> lXh + lXl; each thread: 1 pt x 2 segs ----
  {
    const int ept = tid & 63, sg2 = tid >> 6;
    const float* ip = input + (size_t)(gpt0 + ept) * 3;
    float x0 = ip[0] * SCALE_F, x1 = ip[1] * SCALE_F, x2 = ip[2] * SCALE_F;
    #pragma unroll
    for (int s = 0; s < 2; ++s) {
      int seg = sg2 * 2 + s;
      float vv[8];
      #pragma unroll
      for (int jj = 0; jj < 8; ++jj) vv[jj] = peval(x0, x1, x2, seg * 8 + jj);
      hf c0=(hf)vv[0], c1=(hf)vv[1], c2=(hf)vv[2], c3=(hf)vv[3];
      hf c4=(hf)vv[4], c5=(hf)vv[5], c6=(hf)vv[6], c7=(hf)vv[7];
      *(uint4*)&lXh[ept * 256 + ((seg ^ (ept & 7)) << 3)] =
          make_uint4(pk2h(c0,c1), pk2h(c2,c3), pk2h(c4,c5), pk2h(c6,c7));
      *(uint2*)&lXl[ept * 256 + ((seg ^ (ept & 15)) << 3)] = make_uint2(
          enc4_fp8((vv[0]-(float)c0)*64.f, (vv[1]-(float)c1)*64.f,
                   (vv[2]-(float)c2)*64.f, (vv[3]-(float)c3)*64.f),
          enc4_fp8((vv[4]-(float)c4)*64.f, (vv[5]-(float)c5)*64.f,
                   (vv[6]-(float)c6)*64.f, (vv[7]-(float)c7)*64.f));
    }
  }
  __syncthreads();

  f32x16 a00, a01, a10, a11;
  hf8 hz = {};
  uint2 uz = make_uint2(0, 0);
  float sp0 = 0.f, sp1 = 0.f;

  // ================= layer 1: pe(64) -> x1 =================
  #pragma unroll
  for (int oi = 0; oi < 2; ++oi)
    #pragma unroll
    for (int q = 0; q < 4; ++q) {
      int o0 = ow * 64 + oi * 32 + q * 8 + h * 4;
      float4 bv = *(const float4*)&b1[o0];
      f32x16& aA = oi ? a10 : a00; f32x16& aB = oi ? a11 : a01;
      aA[q*4+0] = bv.x; aA[q*4+1] = bv.y; aA[q*4+2] = bv.z; aA[q*4+3] = bv.w;
      aB[q*4+0] = bv.x; aB[q*4+1] = bv.y; aB[q*4+2] = bv.z; aB[q*4+3] = bv.w;
    }
  layer_loop<4, false>(wsu, wh8b, lXh, lXl, ptA, ptB, h, wbA, w8i,
                       a00, a01, a10, a11, hz, hz, uz, uz, hz, hz, uz, uz);
  __syncthreads();                        // all waves done reading pe slots
  #pragma unroll
  for (int oi = 0; oi < 2; ++oi)
    #pragma unroll
    for (int q = 0; q < 4; ++q) {
      int o0 = ow * 64 + oi * 32 + q * 8 + h * 4;
      float4 f4 = *(const float4*)&snb[o0];
      float4 p4 = *(const float4*)&snb[512 + o0];
      float fr0 = __builtin_fmaf(f4.x, C15R, C30R), fr1 = __builtin_fmaf(f4.y, C15R, C30R);
      float fr2 = __builtin_fmaf(f4.z, C15R, C30R), fr3 = __builtin_fmaf(f4.w, C15R, C30R);
      float pr0 = p4.x * INV2PI, pr1 = p4.y * INV2PI, pr2 = p4.z * INV2PI, pr3 = p4.w * INV2PI;
      int slot = ow * 8 + oi * 4 + q;
      #pragma unroll
      for (int pi = 0; pi < 2; ++pi) {
        const f32x16& a = pi ? (oi ? a11 : a01) : (oi ? a10 : a00);
        float v0 = sinrev(__builtin_fmaf(fr0, a[q*4+0], pr0));
        float v1 = sinrev(__builtin_fmaf(fr1, a[q*4+1], pr1));
        float v2 = sinrev(__builtin_fmaf(fr2, a[q*4+2], pr2));
        float v3 = sinrev(__builtin_fmaf(fr3, a[q*4+3], pr3));
        store4(lXh, lXl, pi ? ptB : ptA, slot, h, v0, v1, v2, v3);
      }
    }
  __syncthreads();

  // ================= layer 2: x1 -> x2, sigma =================
  #pragma unroll
  for (int oi = 0; oi < 2; ++oi)
    #pragma unroll
    for (int q = 0; q < 4; ++q) {
      int o0 = ow * 64 + oi * 32 + q * 8 + h * 4;
      float4 bv = *(const float4*)&b2[o0];
      f32x16& aA = oi ? a10 : a00; f32x16& aB = oi ? a11 : a01;
      aA[q*4+0] = bv.x; aA[q*4+1] = bv.y; aA[q*4+2] = bv.z; aA[q*4+3] = bv.w;
      aB[q*4+0] = bv.x; aB[q*4+1] = bv.y; aB[q*4+2] = bv.z; aB[q*4+3] = bv.w;
    }
  layer_loop<16, false>(wsu + 32768, wh8b + 4 * 4096, lXh, lXl, ptA, ptB, h, wbA, w8i,
                        a00, a01, a10, a11, hz, hz, uz, uz, hz, hz, uz, uz);
  __syncthreads();                        // all waves done reading x1 slots
  #pragma unroll
  for (int oi = 0; oi < 2; ++oi)
    #pragma unroll
    for (int q = 0; q < 4; ++q) {
      int o0 = ow * 64 + oi * 32 + q * 8 + h * 4;
      float4 f4 = *(const float4*)&snb[256 + o0];
      float4 p4 = *(const float4*)&snb[768 + o0];
      float4 wf = *(const float4*)&Wf[o0];
      float fr0 = __builtin_fmaf(f4.x, C15R, C30R), fr1 = __builtin_fmaf(f4.y, C15R, C30R);
      float fr2 = __builtin_fmaf(f4.z, C15R, C30R), fr3 = __builtin_fmaf(f4.w, C15R, C30R);
      float pr0 = p4.x * INV2PI, pr1 = p4.y * INV2PI, pr2 = p4.z * INV2PI, pr3 = p4.w * INV2PI;
      int slot = ow * 8 + oi * 4 + q;
      #pragma unroll
      for (int pi = 0; pi < 2; ++pi) {
        const f32x16& a = pi ? (oi ? a11 : a01) : (oi ? a10 : a00);
        float v0 = sinrev(__builtin_fmaf(fr0, a[q*4+0], pr0));
        float v1 = sinrev(__builtin_fmaf(fr1, a[q*4+1], pr1));
        float v2 = sinrev(__builtin_fmaf(fr2, a[q*4+2], pr2));
        float v3 = sinrev(__builtin_fmaf(fr3, a[q*4+3], pr3));
        float s = __builtin_fmaf(wf.x, v0, __builtin_fmaf(wf.y, v1,
                  __builtin_fmaf(wf.z, v2, wf.w * v3)));
        if (pi == 0) sp0 += s; else sp1 += s;
        store4(lXh, lXl, pi ? ptB : ptA, slot, h, v0, v1, v2, v3);
      }
    }
  __syncthreads();

  // de B-frags in named registers (both points; residual pre-encoded fp8)
  hf8 dhA0, dhA1, dhB0, dhB1; uint2 dlA0, dlA1, dlB0, dlB1;
  build_de(rA0, rA1, rA2, 0 * 16 + h * 8, dhA0, dlA0);
  build_de(rA0, rA1, rA2, 1 * 16 + h * 8, dhA1, dlA1);
  build_de(rB0, rB1, rB2, 0 * 16 + h * 8, dhB0, dlB0);
  build_de(rB0, rB1, rB2, 1 * 16 + h * 8, dhB1, dlB1);

  // ================= layer 3: [x2(256)|de(32)] -> hc, rgb =================
  #pragma unroll
  for (int oi = 0; oi < 2; ++oi)
    #pragma unroll
    for (int q = 0; q < 4; ++q) {
      int o0 = ow * 64 + oi * 32 + q * 8 + h * 4;
      float4 bv = *(const float4*)&bcs[o0];
      f32x16& aA = oi ? a10 : a00; f32x16& aB = oi ? a11 : a01;
      aA[q*4+0] = bv.x; aA[q*4+1] = bv.y; aA[q*4+2] = bv.z; aA[q*4+3] = bv.w;
      aB[q*4+0] = bv.x; aB[q*4+1] = bv.y; aB[q*4+2] = bv.z; aB[q*4+3] = bv.w;
    }
  layer_loop<18, true>(wsu + 163840, wh8b + 20 * 4096, lXh, lXl, ptA, ptB, h, wbA, w8i,
                       a00, a01, a10, a11,
                       dhA0, dhA1, dlA0, dlA1, dhB0, dhB1, dlB0, dlB1);
  float q00 = 0.f, q01 = 0.f, q02 = 0.f, q10 = 0.f, q11 = 0.f, q12 = 0.f;
  #pragma unroll
  for (int oi = 0; oi < 2; ++oi)
    #pragma unroll
    for (int q = 0; q < 4; ++q) {
      int o0 = ow * 64 + oi * 32 + q * 8 + h * 4;
      float4 f4 = *(const float4*)&scb[o0];
      float4 p4 = *(const float4*)&scb[256 + o0];
      float4 w0 = *(const float4*)&Wcl[o0];
      float4 w1 = *(const float4*)&Wcl[256 + o0];
      float4 w2 = *(const float4*)&Wcl[512 + o0];
      float fr0 = __builtin_fmaf(f4.x, C15R, C30R), fr1 = __builtin_fmaf(f4.y, C15R, C30R);
      float fr2 = __builtin_fmaf(f4.z, C15R, C30R), fr3 = __builtin_fmaf(f4.w, C15R, C30R);
      float pr0 = p4.x * INV2PI, pr1 = p4.y * INV2PI, pr2 = p4.z * INV2PI, pr3 = p4.w * INV2PI;
      #pragma unroll
      for (int pi = 0; pi < 2; ++pi) {
        const f32x16& a = pi ? (oi ? a11 : a01) : (oi ? a10 : a00);
        float v0 = sinrev(__builtin_fmaf(fr0, a[q*4+0], pr0));
        float v1 = sinrev(__builtin_fmaf(fr1, a[q*4+1], pr1));
        float v2 = sinrev(__builtin_fmaf(fr2, a[q*4+2], pr2));
        float v3 = sinrev(__builtin_fmaf(fr3, a[q*4+3], pr3));
        float t0 = __builtin_fmaf(w0.x, v0, __builtin_fmaf(w0.y, v1, __builtin_fmaf(w0.z, v2, w0.w * v3)));
        float t1 = __builtin_fmaf(w1.x, v0, __builtin_fmaf(w1.y, v1, __builtin_fmaf(w1.z, v2, w1.w * v3)));
        float t2 = __builtin_fmaf(w2.x, v0, __builtin_fmaf(w2.y, v1, __builtin_fmaf(w2.z, v2, w2.w * v3)));
        if (pi == 0) { q00 += t0; q01 += t1; q02 += t2; }
        else         { q10 += t0; q11 += t1; q12 += t2; }
      }
    }

  // combine h halves, publish per-wave partials (lX fully consumed; lP aliases)
  q00 += __shfl_xor(q00, 32); q01 += __shfl_xor(q01, 32); q02 += __shfl_xor(q02, 32);
  q10 += __shfl_xor(q10, 32); q11 += __shfl_xor(q11, 32); q12 += __shfl_xor(q12, 32);
  sp0 += __shfl_xor(sp0, 32); sp1 += __shfl_xor(sp1, 32);
  __syncthreads();                        // lX reads done before lP alias write
  if (h == 0) {
    *(float4*)&lP[((ow * 64) + l31) * 4]      = make_float4(q00, q01, q02, sp0);
    *(float4*)&lP[((ow * 64) + 32 + l31) * 4] = make_float4(q10, q11, q12, sp1);
  }
  __syncthreads();

  // ---- epilogue: sum the 4 ow waves, add bias, store (256 thr = 64 pts x 4 ch) ----
  {
    int ptL = tid >> 2, ch = tid & 3;
    float v = 0.f;
    #pragma unroll
    for (int owt = 0; owt < 4; ++owt)
      v += lP[((owt * 64) + ptL) * 4 + ch];
    v += (ch == 3) ? bfp[0] : bcl[ch];
    out[((size_t)gpt0 + ptL) * 4 + ch] = v;
  }
}

extern "C" void kernel_launch(void* const* d_in, const int* in_sizes, int n_in,
                              void* d_out, int out_size, void* d_ws, size_t ws_size,
                              hipStream_t stream) {
  const float* input = (const float*)d_in[0];
  const float* rdir  = (const float*)d_in[1];
  const float* sn    = (const float*)d_in[2];
  const float* sc    = (const float*)d_in[3];
  const float* W1    = (const float*)d_in[4];
  const float* b1    = (const float*)d_in[5];
  const float* W2    = (const float*)d_in[6];
  const float* b2    = (const float*)d_in[7];
  const float* Wf    = (const float*)d_in[8];
  const float* bf    = (const float*)d_in[9];
  const float* Wcs   = (const float*)d_in[10];
  const float* bcs   = (const float*)d_in[11];
  const float* Wcl   = (const float*)d_in[12];
  const float* bcl   = (const float*)d_in[13];
  unsigned short* wsu = (unsigned short*)d_ws;
  float* out = (float*)d_out;

  prep_w<<<608, 256, 0, stream>>>(W1, W2, Wcs, wsu);
  siren_mfma<<<4096, 256, 0, stream>>>(input, rdir, sn, sc, b1, b2, Wf, bf,
                                       bcs, Wcl, bcl, wsu, out);
}

// Round 17
// 282.913 us; speedup vs baseline: 1.0379x; 1.0379x over previous
//
#include <hip/hip_runtime.h>

// ShallowSIRENWithPosEmb — fp16 hi + fp8-residual X fed DIRECTLY to fp8 MFMA.
// Terms: D = Wh(f16)*Xh(f16) + Wl'(f16,x2^10)*(Xh*2^-10) + (Wh*2^-6 bf8)*(Xl*2^6 fp8).
// R17 = R15 verbatim (session best: 283us, no spill). R16's setprio regressed
// (WRITE 20->136MB scheduler-perturbation spill) and is reverted.
// 64 pts/block, 256 thr, 12 MFMA/kstep, no K-loop barriers, LDS 48KB -> 3 blocks/CU.

#define SCALE_F 8.333333333333334f   // 2/0.24

typedef _Float16 hf;
typedef __attribute__((ext_vector_type(2)))  float f32x2;
typedef __attribute__((ext_vector_type(2)))  _Float16 hf2;
typedef __attribute__((ext_vector_type(8)))  _Float16 hf8;
typedef __attribute__((ext_vector_type(16))) float f32x16;

#define WH8_BASE 311296   // ushort offset of bf8 Wh plane in d_ws

// ---- Cody-Waite sin/cos in radians (embeds: args up to ~2e4) ----
__device__ __forceinline__ float redrev(float x) {
  const float chi = 0.15915494309189535f;
  const float clo = 6.4206383e-09f;
  float n = rintf(x * chi);
  float d = __builtin_fmaf(x, chi, -n);
  return __builtin_fmaf(x, clo, d);
}
__device__ __forceinline__ float fsin(float x) { return __builtin_amdgcn_sinf(redrev(x)); }
__device__ __forceinline__ float fcos(float x) { return __builtin_amdgcn_cosf(redrev(x)); }
// rev-space film sin: v_fract + v_sin (sin periodic in 1 rev)
__device__ __forceinline__ float sinrev(float t) {
  return __builtin_amdgcn_sinf(t - floorf(t));
}

#define INV2PI 0.15915494309189535f
#define C15R   2.3873241463784303f   // 15/(2pi)
#define C30R   4.7746482927568605f   // 30/(2pi)

__device__ __forceinline__ unsigned pk2h(hf a, hf b) {
  return ((unsigned)__builtin_bit_cast(unsigned short, a)) |
         (((unsigned)__builtin_bit_cast(unsigned short, b)) << 16);
}
// fp8 e4m3 encode (HW): 4 floats -> 4 bytes
__device__ __forceinline__ unsigned enc4_fp8(float r0, float r1, float r2, float r3) {
  int e = __builtin_amdgcn_cvt_pk_fp8_f32(r0, r1, 0, false);
  e = __builtin_amdgcn_cvt_pk_fp8_f32(r2, r3, e, true);
  return (unsigned)e;
}

// ---- weight prep: fp16 hi + (lo*2^10) slabs + bf8 (hi*2^-6) pair-plane ----
// fp16 slab (8192 ushort/kstep): [hi:4096][lo:4096]; r = [ot:8][kh:2][o5:32][j:8]
// bf8 plane (4096 B/kstep): [ow:4][kh:2][o5:32][oi:2][j:8] -> lane reads ONE uint4.
// L1 slabs 0-3; L2 4-19; L3 20-37 (K=[x2(256)|de27 pad5]).
__global__ void prep_w(const float* __restrict__ W1, const float* __restrict__ W2,
                       const float* __restrict__ Wcs, unsigned short* __restrict__ wsu)
{
  int t = blockIdx.x * 256 + threadIdx.x;
  if (t >= 155648) return;
  int L, pos, base;
  if (t < 16384)      { L = 0; pos = t;         base = 0; }
  else if (t < 81920) { L = 1; pos = t - 16384; base = 32768; }
  else                { L = 2; pos = t - 81920; base = 163840; }
  int kstep = pos >> 12, r = pos & 4095;
  int ot = (r >> 9) & 7, kh = (r >> 8) & 1, o5 = (r >> 3) & 31, j = r & 7;
  int o = ot * 32 + o5, k = kstep * 16 + kh * 8 + j;
  float wv = 0.f;
  if (L == 0)      { if (k < 63) wv = W1[o * 63 + k]; }
  else if (L == 1) { wv = W2[o * 256 + k]; }
  else { if (k < 256) wv = Wcs[o * 283 + 27 + k];
         else { int q = k - 256; if (q < 27) wv = Wcs[o * 283 + q]; } }
  hf hh = (hf)wv;
  hf ll = (hf)((wv - (float)hh) * 1024.0f);
  wsu[base + kstep * 8192 + r]        = __builtin_bit_cast(unsigned short, hh);
  wsu[base + kstep * 8192 + 4096 + r] = __builtin_bit_cast(unsigned short, ll);
  // bf8 plane: Wh * 2^-6 (e5m2), pair layout for 16B lane loads
  int slab = (base >> 13) + kstep;
  int ow2 = ot >> 1, oi = ot & 1;
  int na = ow2 * 1024 + kh * 512 + o5 * 16 + oi * 8 + j;
  unsigned char b8 = (unsigned char)(__builtin_amdgcn_cvt_pk_bf8_f32(
                         (float)hh * 0.015625f, 0.f, 0, false) & 0xff);
  ((unsigned char*)(wsu + WH8_BASE))[slab * 4096 + na] = b8;
}

__device__ __forceinline__ float peval(float x0, float x1, float x2, int k) {
  if (k >= 63) return 0.f;
  if (k < 3) return (k == 0) ? x0 : ((k == 1) ? x1 : x2);
  int rr = k - 3, f = rr / 6, rem = rr - f * 6;
  int d = (rem < 3) ? rem : rem - 3;
  float xa = (d == 0) ? x0 : ((d == 1) ? x1 : x2);
  float arg = xa * (float)(1 << f);
  return (rem < 3) ? fsin(arg) : fcos(arg);
}
__device__ __forceinline__ float deval(float r0, float r1, float r2, int k) {
  if (k >= 27) return 0.f;
  if (k < 3) return (k == 0) ? r0 : ((k == 1) ? r1 : r2);
  int rr = k - 3, f = rr / 6, rem = rr - f * 6;
  int d = (rem < 3) ? rem : rem - 3;
  float ra = (d == 0) ? r0 : ((d == 1) ? r1 : r2);
  float arg = ra * (float)(1 << f);
  return (rem < 3) ? fsin(arg) : fcos(arg);
}
// de B-frags: hi fp16 + residual packed as fp8 e4m3 (x2^6), register-resident
__device__ __forceinline__ void build_de(float r0, float r1, float r2, int kbase,
                                         hf8& hh, uint2& lenc) {
  unsigned uh[4]; float res[8];
  #pragma unroll
  for (int jj = 0; jj < 4; ++jj) {
    float va = deval(r0, r1, r2, kbase + 2 * jj), vb = deval(r0, r1, r2, kbase + 2 * jj + 1);
    hf ha = (hf)va, hb = (hf)vb;
    uh[jj] = pk2h(ha, hb);
    res[2 * jj]     = (va - (float)ha) * 64.f;
    res[2 * jj + 1] = (vb - (float)hb) * 64.f;
  }
  uint4 vh = make_uint4(uh[0], uh[1], uh[2], uh[3]);
  hh = __builtin_bit_cast(hf8, vh);
  lenc = make_uint2(enc4_fp8(res[0], res[1], res[2], res[3]),
                    enc4_fp8(res[4], res[5], res[6], res[7]));
}

// ---- one kstep: 12 MFMAs (2 ot x 2 pt x 3 terms); term3 = bf8_fp8 direct ----
__device__ __forceinline__ void kstep_mfma(uint4 uh0, uint4 uh1, uint4 ul0, uint4 ul1,
                                           uint4 w8q,
                                           hf8 BhA, uint2 BlA, hf8 BhB, uint2 BlB,
                                           f32x16& a00, f32x16& a01,
                                           f32x16& a10, f32x16& a11) {
  const hf sc = (hf)0.0009765625f;               // 2^-10, exact
  hf8 BhsA = BhA * sc, BhsB = BhB * sc;
  hf8 Ah0 = __builtin_bit_cast(hf8, uh0);
  hf8 Ah1 = __builtin_bit_cast(hf8, uh1);
  hf8 Al0 = __builtin_bit_cast(hf8, ul0);
  hf8 Al1 = __builtin_bit_cast(hf8, ul1);
  long A80 = __builtin_bit_cast(long, make_uint2(w8q.x, w8q.y));
  long A81 = __builtin_bit_cast(long, make_uint2(w8q.z, w8q.w));
  long B8A = __builtin_bit_cast(long, BlA), B8B = __builtin_bit_cast(long, BlB);
  a00 = __builtin_amdgcn_mfma_f32_32x32x16_f16(Ah0, BhA,  a00, 0, 0, 0);
  a10 = __builtin_amdgcn_mfma_f32_32x32x16_f16(Ah1, BhA,  a10, 0, 0, 0);
  a01 = __builtin_amdgcn_mfma_f32_32x32x16_f16(Ah0, BhB,  a01, 0, 0, 0);
  a11 = __builtin_amdgcn_mfma_f32_32x32x16_f16(Ah1, BhB,  a11, 0, 0, 0);
  a00 = __builtin_amdgcn_mfma_f32_32x32x16_f16(Al0, BhsA, a00, 0, 0, 0);
  a10 = __builtin_amdgcn_mfma_f32_32x32x16_f16(Al1, BhsA, a10, 0, 0, 0);
  a01 = __builtin_amdgcn_mfma_f32_32x32x16_f16(Al0, BhsB, a01, 0, 0, 0);
  a11 = __builtin_amdgcn_mfma_f32_32x32x16_f16(Al1, BhsB, a11, 0, 0, 0);
  a00 = __builtin_amdgcn_mfma_f32_32x32x16_bf8_fp8(A80, B8A, a00, 0, 0, 0);
  a10 = __builtin_amdgcn_mfma_f32_32x32x16_bf8_fp8(A81, B8A, a10, 0, 0, 0);
  a01 = __builtin_amdgcn_mfma_f32_32x32x16_bf8_fp8(A80, B8B, a01, 0, 0, 0);
  a11 = __builtin_amdgcn_mfma_f32_32x32x16_bf8_fp8(A81, B8B, a11, 0, 0, 0);
}

// ---- one layer: NK ksteps, no barriers; W (incl bf8) prefetched 1 kstep ahead,
//      B-frags loaded at kstep top (R12 pattern — no extra live state) ----
template <int NK, bool DE>
__device__ __forceinline__ void layer_loop(
    const unsigned short* __restrict__ prep, const unsigned char* __restrict__ wh8,
    const unsigned short* lXh, const unsigned char* lXl,
    int ptA, int ptB, int h, int wbA, int w8i,
    f32x16& a00, f32x16& a01, f32x16& a10, f32x16& a11,
    hf8 dhA0, hf8 dhA1, uint2 dlA0, uint2 dlA1,
    hf8 dhB0, hf8 dhB1, uint2 dlB0, uint2 dlB1)
{
  const int bhA = ptA * 256, pA7 = ptA & 7, pA15 = ptA & 15;
  const int bhB = ptB * 256, pB7 = ptB & 7, pB15 = ptB & 15;
  const uint4* wp = (const uint4*)prep;
  const uint4* w8p = (const uint4*)wh8;
  const int wi = wbA >> 3;
  uint4 h0 = wp[wi], h1 = wp[wi + 64];
  uint4 l0 = wp[wi + 512], l1 = wp[wi + 576];
  uint4 w8 = w8p[w8i];
  #pragma unroll 2
  for (int ks = 0; ks < NK; ++ks) {
    uint4 nh0, nh1, nl0, nl1, nw8;
    if (ks + 1 < NK) {                     // prefetch next kstep's W frags (5 x 16B)
      const uint4* np = wp + (size_t)(ks + 1) * 1024;
      nh0 = np[wi]; nh1 = np[wi + 64]; nl0 = np[wi + 512]; nl1 = np[wi + 576];
      nw8 = w8p[(ks + 1) * 256 + w8i];
    }
    hf8 BhA, BhB; uint2 BlA, BlB;
    if (!DE || ks < NK - 2) {
      int slot = ks * 2 + h;
      BhA = *(const hf8*)&lXh[bhA + ((slot ^ pA7) << 3)];
      BhB = *(const hf8*)&lXh[bhB + ((slot ^ pB7) << 3)];
      BlA = *(const uint2*)&lXl[bhA + ((slot ^ pA15) << 3)];
      BlB = *(const uint2*)&lXl[bhB + ((slot ^ pB15) << 3)];
    } else if (ks == NK - 2) {
      BhA = dhA0; BlA = dlA0; BhB = dhB0; BlB = dlB0;
    } else {
      BhA = dhA1; BlA = dlA1; BhB = dhB1; BlB = dlB1;
    }
    kstep_mfma(h0, h1, l0, l1, w8, BhA, BlA, BhB, BlB, a00, a01, a10, a11);
    h0 = nh0; h1 = nh1; l0 = nl0; l1 = nl1; w8 = nw8;
  }
}

// store 4 film outputs: fp16 hi (8B) + fp8 residual (4B)
__device__ __forceinline__ void store4(unsigned short* lXh, unsigned char* lXl,
                                       int pt, int slot, int h,
                                       float v0, float v1, float v2, float v3)
{
  hf h0 = (hf)v0, h1 = (hf)v1, h2 = (hf)v2, h3 = (hf)v3;
  *(uint2*)&lXh[pt * 256 + ((slot ^ (pt & 7)) << 3) + h * 4] =
      make_uint2(pk2h(h0, h1), pk2h(h2, h3));
  *(unsigned*)&lXl[pt * 256 + ((slot ^ (pt & 15)) << 3) + h * 4] =
      enc4_fp8((v0 - (float)h0) * 64.f, (v1 - (float)h1) * 64.f,
               (v2 - (float)h2) * 64.f, (v3 - (float)h3) * 64.f);
}

__global__ void __launch_bounds__(256, 3)
siren_mfma(const float* __restrict__ input, const float* __restrict__ rdir,
           const float* __restrict__ sn, const float* __restrict__ sc,
           const float* __restrict__ b1, const float* __restrict__ b2,
           const float* __restrict__ Wf, const float* __restrict__ bfp,
           const float* __restrict__ bcs, const float* __restrict__ Wcl,
           const float* __restrict__ bcl, const unsigned short* __restrict__ wsu,
           float* __restrict__ out)
{
  __shared__ __align__(16) unsigned char smem[49152];   // 48KB -> 3 blocks/CU
  unsigned short* lXh = (unsigned short*)smem;          // 32KB [pt:64][256 fp16]
  unsigned char*  lXl = smem + 32768;                   // 16KB [pt:64][256 fp8]
  float* lP = (float*)smem;                             // epilogue alias

  const int tid = threadIdx.x;
  const int ow = tid >> 6, lane = tid & 63;             // 4 waves = 4 out-quarters
  const int l31 = lane & 31, h = lane >> 5;
  const int gpt0 = blockIdx.x << 6;                     // 64 pts/block
  const int b = blockIdx.x >> 10;                       // 1024 blocks per batch
  const int ptA = l31, ptB = 32 + l31;
  const int wbA = ow * 1024 + h * 256 + l31 * 8;        // fp16 A-frag base (ushorts)
  const int w8i = ow * 64 + h * 32 + l31;               // bf8 pair-frag uint4 index
  const float* snb = sn + b * 1024;
  const float* scb = sc + b * 512;
  const unsigned char* wh8b = (const unsigned char*)(wsu + WH8_BASE);

  float rA0, rA1, rA2, rB0, rB1, rB2;
  {
    const float* rp = rdir + (size_t)(gpt0 + ptA) * 3;
    rA0 = rp[0]; rA1 = rp[1]; rA2 = rp[2];
    const float* rq = rdir + (size_t)(gpt0 + ptB) * 3;
    rB0 = rq[0]; rB1 = rq[1]; rB2 = rq[2];
  }

  // ---- embed: pe (K=64, k=63 pad) -> lXh + lXl; each thread: 1 pt x 2 segs ----
  {
    const int ept = tid & 63, sg2 = tid >> 6;
    const float* ip = input + (size_t)(gpt0 + ept) * 3;
    float x0 = ip[0] * SCALE_F, x1 = ip[1] * SCALE_F, x2 = ip[2] * SCALE_F;
    #pragma unroll
    for (int s = 0; s < 2; ++s) {
      int seg = sg2 * 2 + s;
      float vv[8];
      #pragma unroll
      for (int jj = 0; jj < 8; ++jj) vv[jj] = peval(x0, x1, x2, seg * 8 + jj);
      hf c0=(hf)vv[0], c1=(hf)vv[1], c2=(hf)vv[2], c3=(hf)vv[3];
      hf c4=(hf)vv[4], c5=(hf)vv[5], c6=(hf)vv[6], c7=(hf)vv[7];
      *(uint4*)&lXh[ept * 256 + ((seg ^ (ept & 7)) << 3)] =
          make_uint4(pk2h(c0,c1), pk2h(c2,c3), pk2h(c4,c5), pk2h(c6,c7));
      *(uint2*)&lXl[ept * 256 + ((seg ^ (ept & 15)) << 3)] = make_uint2(
          enc4_fp8((vv[0]-(float)c0)*64.f, (vv[1]-(float)c1)*64.f,
                   (vv[2]-(float)c2)*64.f, (vv[3]-(float)c3)*64.f),
          enc4_fp8((vv[4]-(float)c4)*64.f, (vv[5]-(float)c5)*64.f,
                   (vv[6]-(float)c6)*64.f, (vv[7]-(float)c7)*64.f));
    }
  }
  __syncthreads();

  f32x16 a00, a01, a10, a11;
  hf8 hz = {};
  uint2 uz = make_uint2(0, 0);
  float sp0 = 0.f, sp1 = 0.f;

  // ================= layer 1: pe(64) -> x1 =================
  #pragma unroll
  for (int oi = 0; oi < 2; ++oi)
    #pragma unroll
    for (int q = 0; q < 4; ++q) {
      int o0 = ow * 64 + oi * 32 + q * 8 + h * 4;
      float4 bv = *(const float4*)&b1[o0];
      f32x16& aA = oi ? a10 : a00; f32x16& aB = oi ? a11 : a01;
      aA[q*4+0] = bv.x; aA[q*4+1] = bv.y; aA[q*4+2] = bv.z; aA[q*4+3] = bv.w;
      aB[q*4+0] = bv.x; aB[q*4+1] = bv.y; aB[q*4+2] = bv.z; aB[q*4+3] = bv.w;
    }
  layer_loop<4, false>(wsu, wh8b, lXh, lXl, ptA, ptB, h, wbA, w8i,
                       a00, a01, a10, a11, hz, hz, uz, uz, hz, hz, uz, uz);
  __syncthreads();                        // all waves done reading pe slots
  #pragma unroll
  for (int oi = 0; oi < 2; ++oi)
    #pragma unroll
    for (int q = 0; q < 4; ++q) {
      int o0 = ow * 64 + oi * 32 + q * 8 + h * 4;
      float4 f4 = *(const float4*)&snb[o0];
      float4 p4 = *(const float4*)&snb[512 + o0];
      float fr0 = __builtin_fmaf(f4.x, C15R, C30R), fr1 = __builtin_fmaf(f4.y, C15R, C30R);
      float fr2 = __builtin_fmaf(f4.z, C15R, C30R), fr3 = __builtin_fmaf(f4.w, C15R, C30R);
      float pr0 = p4.x * INV2PI, pr1 = p4.y * INV2PI, pr2 = p4.z * INV2PI, pr3 = p4.w * INV2PI;
      int slot = ow * 8 + oi * 4 + q;
      #pragma unroll
      for (int pi = 0; pi < 2; ++pi) {
        const f32x16& a = pi ? (oi ? a11 : a01) : (oi ? a10 : a00);
        float v0 = sinrev(__builtin_fmaf(fr0, a[q*4+0], pr0));
        float v1 = sinrev(__builtin_fmaf(fr1, a[q*4+1], pr1));
        float v2 = sinrev(__builtin_fmaf(fr2, a[q*4+2], pr2));
        float v3 = sinrev(__builtin_fmaf(fr3, a[q*4+3], pr3));
        store4(lXh, lXl, pi ? ptB : ptA, slot, h, v0, v1, v2, v3);
      }
    }
  __syncthreads();

  // ================= layer 2: x1 -> x2, sigma =================
  #pragma unroll
  for (int oi = 0; oi < 2; ++oi)
    #pragma unroll
    for (int q = 0; q < 4; ++q) {
      int o0 = ow * 64 + oi * 32 + q * 8 + h * 4;
      float4 bv = *(const float4*)&b2[o0];
      f32x16& aA = oi ? a10 : a00; f32x16& aB = oi ? a11 : a01;
      aA[q*4+0] = bv.x; aA[q*4+1] = bv.y; aA[q*4+2] = bv.z; aA[q*4+3] = bv.w;
      aB[q*4+0] = bv.x; aB[q*4+1] = bv.y; aB[q*4+2] = bv.z; aB[q*4+3] = bv.w;
    }
  layer_loop<16, false>(wsu + 32768, wh8b + 4 * 4096, lXh, lXl, ptA, ptB, h, wbA, w8i,
                        a00, a01, a10, a11, hz, hz, uz, uz, hz, hz, uz, uz);
  __syncthreads();                        // all waves done reading x1 slots
  #pragma unroll
  for (int oi = 0; oi < 2; ++oi)
    #pragma unroll
    for (int q = 0; q < 4; ++q) {
      int o0 = ow * 64 + oi * 32 + q * 8 + h * 4;
      float4 f4 = *(const float4*)&snb[256 + o0];
      float4 p4 = *(const float4*)&snb[768 + o0];
      float4 wf = *(const float4*)&Wf[o0];
      float fr0 = __builtin_fmaf(f4.x, C15R, C30R), fr1 = __builtin_fmaf(f4.y, C15R, C30R);
      float fr2 = __builtin_fmaf(f4.z, C15R, C30R), fr3 = __builtin_fmaf(f4.w, C15R, C30R);
      float pr0 = p4.x * INV2PI, pr1 = p4.y * INV2PI, pr2 = p4.z * INV2PI, pr3 = p4.w * INV2PI;
      int slot = ow * 8 + oi * 4 + q;
      #pragma unroll
      for (int pi = 0; pi < 2; ++pi) {
        const f32x16& a = pi ? (oi ? a11 : a01) : (oi ? a10 : a00);
        float v0 = sinrev(__builtin_fmaf(fr0, a[q*4+0], pr0));
        float v1 = sinrev(__builtin_fmaf(fr1, a[q*4+1], pr1));
        float v2 = sinrev(__builtin_fmaf(fr2, a[q*4+2], pr2));
        float v3 = sinrev(__builtin_fmaf(fr3, a[q*4+3], pr3));
        float s = __builtin_fmaf(wf.x, v0, __builtin_fmaf(wf.y, v1,
                  __builtin_fmaf(wf.z, v2, wf.w * v3)));
        if (pi == 0) sp0 += s; else sp1 += s;
        store4(lXh, lXl, pi ? ptB : ptA, slot, h, v0, v1, v2, v3);
      }
    }
  __syncthreads();

  // de B-frags in named registers (both points; residual pre-encoded fp8)
  hf8 dhA0, dhA1, dhB0, dhB1; uint2 dlA0, dlA1, dlB0, dlB1;
  build_de(rA0, rA1, rA2, 0 * 16 + h * 8, dhA0, dlA0);
  build_de(rA0, rA1, rA2, 1 * 16 + h * 8, dhA1, dlA1);
  build_de(rB0, rB1, rB2, 0 * 16 + h * 8, dhB0, dlB0);
  build_de(rB0, rB1, rB2, 1 * 16 + h * 8, dhB1, dlB1);

  // ================= layer 3: [x2(256)|de(32)] -> hc, rgb =================
  #pragma unroll
  for (int oi = 0; oi < 2; ++oi)
    #pragma unroll
    for (int q = 0; q < 4; ++q) {
      int o0 = ow * 64 + oi * 32 + q * 8 + h * 4;
      float4 bv = *(const float4*)&bcs[o0];
      f32x16& aA = oi ? a10 : a00; f32x16& aB = oi ? a11 : a01;
      aA[q*4+0] = bv.x; aA[q*4+1] = bv.y; aA[q*4+2] = bv.z; aA[q*4+3] = bv.w;
      aB[q*4+0] = bv.x; aB[q*4+1] = bv.y; aB[q*4+2] = bv.z; aB[q*4+3] = bv.w;
    }
  layer_loop<18, true>(wsu + 163840, wh8b + 20 * 4096, lXh, lXl, ptA, ptB, h, wbA, w8i,
                       a00, a01, a10, a11,
                       dhA0, dhA1, dlA0, dlA1, dhB0, dhB1, dlB0, dlB1);
  float q00 = 0.f, q01 = 0.f, q02 = 0.f, q10 = 0.f, q11 = 0.f, q12 = 0.f;
  #pragma unroll
  for (int oi = 0; oi < 2; ++oi)
    #pragma unroll
    for (int q = 0; q < 4; ++q) {
      int o0 = ow * 64 + oi * 32 + q * 8 + h * 4;
      float4 f4 = *(const float4*)&scb[o0];
      float4 p4 = *(const float4*)&scb[256 + o0];
      float4 w0 = *(const float4*)&Wcl[o0];
      float4 w1 = *(const float4*)&Wcl[256 + o0];
      float4 w2 = *(const float4*)&Wcl[512 + o0];
      float fr0 = __builtin_fmaf(f4.x, C15R, C30R), fr1 = __builtin_fmaf(f4.y, C15R, C30R);
      float fr2 = __builtin_fmaf(f4.z, C15R, C30R), fr3 = __builtin_fmaf(f4.w, C15R, C30R);
      float pr0 = p4.x * INV2PI, pr1 = p4.y * INV2PI, pr2 = p4.z * INV2PI, pr3 = p4.w * INV2PI;
      #pragma unroll
      for (int pi = 0; pi < 2; ++pi) {
        const f32x16& a = pi ? (oi ? a11 : a01) : (oi ? a10 : a00);
        float v0 = sinrev(__builtin_fmaf(fr0, a[q*4+0], pr0));
        float v1 = sinrev(__builtin_fmaf(fr1, a[q*4+1], pr1));
        float v2 = sinrev(__builtin_fmaf(fr2, a[q*4+2], pr2));
        float v3 = sinrev(__builtin_fmaf(fr3, a[q*4+3], pr3));
        float t0 = __builtin_fmaf(w0.x, v0, __builtin_fmaf(w0.y, v1, __builtin_fmaf(w0.z, v2, w0.w * v3)));
        float t1 = __builtin_fmaf(w1.x, v0, __builtin_fmaf(w1.y, v1, __builtin_fmaf(w1.z, v2, w1.w * v3)));
        float t2 = __builtin_fmaf(w2.x, v0, __builtin_fmaf(w2.y, v1, __builtin_fmaf(w2.z, v2, w2.w * v3)));
        if (pi == 0) { q00 += t0; q01 += t1; q02 += t2; }
        else         { q10 += t0; q11 += t1; q12 += t2; }
      }
    }

  // combine h halves, publish per-wave partials (lX fully consumed; lP aliases)
  q00 += __shfl_xor(q00, 32); q01 += __shfl_xor(q01, 32); q02 += __shfl_xor(q02, 32);
  q10 += __shfl_xor(q10, 32); q11 += __shfl_xor(q11, 32); q12 += __shfl_xor(q12, 32);
  sp0 += __shfl_xor(sp0, 32); sp1 += __shfl_xor(sp1, 32);
  __syncthreads();                        // lX reads done before lP alias write
  if (h == 0) {
    *(float4*)&lP[((ow * 64) + l31) * 4]      = make_float4(q00, q01, q02, sp0);
    *(float4*)&lP[((ow * 64) + 32 + l31) * 4] = make_float4(q10, q11, q12, sp1);
  }
  __syncthreads();

  // ---- epilogue: sum the 4 ow waves, add bias, store (256 thr = 64 pts x 4 ch) ----
  {
    int ptL = tid >> 2, ch = tid & 3;
    float v = 0.f;
    #pragma unroll
    for (int owt = 0; owt < 4; ++owt)
      v += lP[((owt * 64) + ptL) * 4 + ch];
    v += (ch == 3) ? bfp[0] : bcl[ch];
    out[((size_t)gpt0 + ptL) * 4 + ch] = v;
  }
}

extern "C" void kernel_launch(void* const* d_in, const int* in_sizes, int n_in,
                              void* d_out, int out_size, void* d_ws, size_t ws_size,
                              hipStream_t stream) {
  const float* input = (const float*)d_in[0];
  const float* rdir  = (const float*)d_in[1];
  const float* sn    = (const float*)d_in[2];
  const float* sc    = (const float*)d_in[3];
  const float* W1    = (const float*)d_in[4];
  const float* b1    = (const float*)d_in[5];
  const float* W2    = (const float*)d_in[6];
  const float* b2    = (const float*)d_in[7];
  const float* Wf    = (const float*)d_in[8];
  const float* bf    = (const float*)d_in[9];
  const float* Wcs   = (const float*)d_in[10];
  const float* bcs   = (const float*)d_in[11];
  const float* Wcl   = (const float*)d_in[12];
  const float* bcl   = (const float*)d_in[13];
  unsigned short* wsu = (unsigned short*)d_ws;
  float* out = (float*)d_out;

  prep_w<<<608, 256, 0, stream>>>(W1, W2, Wcs, wsu);
  siren_mfma<<<4096, 256, 0, stream>>>(input, rdir, sn, sc, b1, b2, Wf, bf,
                                       bcs, Wcl, bcl, wsu, out);
}